// Round 1
// baseline (176.329 us; speedup 1.0000x reference)
//
#include <hip/hip_runtime.h>
#include <hip/hip_bf16.h>
#include <stdint.h>

typedef __bf16 bf16x8 __attribute__((ext_vector_type(8)));
typedef float  f32x4  __attribute__((ext_vector_type(4)));

// Geometry:
//  Layer 1: K1 = 784 (25 K-tiles of 32, tail half-valid), N1 = 512 (500 + zero pad)
//  Layer 2: K2 = 512 (500 + pad),                        N2 = 256 (200 + pad)
//  Layer 3: K3 = 256 (200 + pad),                        N3 = 16  (10  + pad)
// B operands are pre-swizzled into MFMA fragment order:
//  slot = (ktile * NF + nfrag), value j of lane l = W[ktile*32 + (l>>4)*8 + j][nfrag*16 + (l&15)]
//  stored at bf16 offset (slot*64 + l)*8  -> one coalesced dwordx4 per fragment.

#define KT1 25
#define NF1 32
#define KT2 16
#define NF2 16
#define KT3 8

// ---- prep: W1eff = conv-folded W1, swizzled bf16 ----
__global__ void prep_w1(const float* __restrict__ W1, const float* __restrict__ cw,
                        __bf16* __restrict__ w1s) {
  int gid  = blockIdx.x * 256 + threadIdx.x;   // 51200 threads total
  int lane = gid & 63;
  int slot = gid >> 6;                         // 0..799
  int t = slot >> 5;                           // k-tile 0..24
  int f = slot & 31;                           // n-frag 0..31
  int kbase = t * 32 + ((lane >> 4) << 3);
  int n = f * 16 + (lane & 15);
  float c[9];
#pragma unroll
  for (int i = 0; i < 9; ++i) c[i] = cw[i];
  bf16x8 v;
#pragma unroll
  for (int e = 0; e < 8; ++e) {
    int k = kbase + e;
    float acc = 0.f;
    if (k < 784 && n < 500) {
      int pi = k / 28, pj = k % 28;
#pragma unroll
      for (int dr = 0; dr < 3; ++dr) {
        int r = pi - dr;
        if (r < 0 || r >= 26) continue;
#pragma unroll
        for (int dc = 0; dc < 3; ++dc) {
          int cc = pj - dc;
          if (cc < 0 || cc >= 26) continue;
          acc += c[dr * 3 + dc] * W1[(size_t)(r * 26 + cc) * 500 + n];
        }
      }
    }
    v[e] = (__bf16)acc;
  }
  *(bf16x8*)(w1s + (size_t)(slot * 64 + lane) * 8) = v;
}

__global__ void prep_w2(const float* __restrict__ W2, __bf16* __restrict__ w2s) {
  int gid  = blockIdx.x * 256 + threadIdx.x;   // 16384 threads
  int lane = gid & 63;
  int slot = gid >> 6;                         // 0..255
  int t = slot >> 4;                           // k-tile 0..15
  int f = slot & 15;                           // n-frag 0..15
  int kbase = t * 32 + ((lane >> 4) << 3);
  int n = f * 16 + (lane & 15);
  bf16x8 v;
#pragma unroll
  for (int e = 0; e < 8; ++e) {
    int k = kbase + e;
    float val = (k < 500 && n < 200) ? W2[(size_t)k * 200 + n] : 0.f;
    v[e] = (__bf16)val;
  }
  *(bf16x8*)(w2s + (size_t)(slot * 64 + lane) * 8) = v;
}

__global__ void prep_w3(const float* __restrict__ W3, __bf16* __restrict__ w3s) {
  int gid  = blockIdx.x * 256 + threadIdx.x;   // 512 threads
  int lane = gid & 63;
  int t    = gid >> 6;                         // k-tile 0..7
  int kbase = t * 32 + ((lane >> 4) << 3);
  int n = lane & 15;
  bf16x8 v;
#pragma unroll
  for (int e = 0; e < 8; ++e) {
    int k = kbase + e;
    float val = (k < 200 && n < 10) ? W3[(size_t)k * 10 + n] : 0.f;
    v[e] = (__bf16)val;
  }
  *(bf16x8*)(w3s + (size_t)(t * 64 + lane) * 8) = v;
}

// ---- fused 3-layer MLP, 32 batch rows per block, 4 waves ----
__global__ __launch_bounds__(256, 3) void mlp_fused(
    const float* __restrict__ x,
    const __bf16* __restrict__ w1s, const __bf16* __restrict__ w2s,
    const __bf16* __restrict__ w3s,
    const float* __restrict__ b1, const float* __restrict__ b2,
    const float* __restrict__ b3,
    float* __restrict__ out)
{
  __shared__ __align__(16) __bf16 h1[32 * 512];  // 32 KB, swizzled
  __shared__ __align__(16) __bf16 h2[32 * 256];  // 16 KB, swizzled
  __shared__ float sb1[512];
  __shared__ float sb2[256];

  const int tid  = threadIdx.x;
  const int lane = tid & 63;
  const int w    = tid >> 6;   // wave 0..3
  const int lrow = lane & 15;
  const int lgrp = lane >> 4;  // 0..3
  const int brow = blockIdx.x * 32;

  // stage biases (zero-padded)
  sb1[tid]       = (tid < 500) ? b1[tid] : 0.f;
  sb1[tid + 256] = (tid + 256 < 500) ? b1[tid + 256] : 0.f;
  sb2[tid]       = (tid < 200) ? b2[tid] : 0.f;

  const f32x4 FZ = {0.f, 0.f, 0.f, 0.f};

  // ---------------- Layer 1: h1 = relu(x @ W1eff + b1) ----------------
  f32x4 acc1[2][8];
#pragma unroll
  for (int m = 0; m < 2; ++m)
#pragma unroll
    for (int f = 0; f < 8; ++f) acc1[m][f] = FZ;

  const float*  xrow0 = x + (size_t)(brow + lrow) * 784 + lgrp * 8;
  const bf16x8* w1p   = (const bf16x8*)w1s + (size_t)(w * 8) * 64 + lane;

#pragma unroll 2
  for (int t = 0; t < KT1; ++t) {
    bf16x8 bfrag[8];
#pragma unroll
    for (int f = 0; f < 8; ++f)
      bfrag[f] = w1p[(size_t)(t * 32 + f) * 64];

    bf16x8 afrag[2];
#pragma unroll
    for (int m = 0; m < 2; ++m) {
      bf16x8 a;
      if (t < KT1 - 1 || lgrp < 2) {     // tail tile: k in [768,800), valid < 784
        const float* ap = xrow0 + (size_t)m * 16 * 784 + t * 32;
        f32x4 u0 = *(const f32x4*)ap;
        f32x4 u1 = *(const f32x4*)(ap + 4);
#pragma unroll
        for (int e = 0; e < 4; ++e) { a[e] = (__bf16)u0[e]; a[e + 4] = (__bf16)u1[e]; }
      } else {
#pragma unroll
        for (int e = 0; e < 8; ++e) a[e] = (__bf16)0.f;
      }
      afrag[m] = a;
    }

#pragma unroll
    for (int f = 0; f < 8; ++f) {
      acc1[0][f] = __builtin_amdgcn_mfma_f32_16x16x32_bf16(afrag[0], bfrag[f], acc1[0][f], 0, 0, 0);
      acc1[1][f] = __builtin_amdgcn_mfma_f32_16x16x32_bf16(afrag[1], bfrag[f], acc1[1][f], 0, 0, 0);
    }
  }

  __syncthreads();  // biases staged; nothing read h1 yet

  // epilogue 1: bias + relu + bf16 -> h1 (XOR-swizzled rows)
#pragma unroll
  for (int m = 0; m < 2; ++m) {
#pragma unroll
    for (int f = 0; f < 8; ++f) {
      int col = w * 128 + f * 16 + lrow;
      float bias = sb1[col];
#pragma unroll
      for (int r = 0; r < 4; ++r) {
        int row = m * 16 + lgrp * 4 + r;
        float v = fmaxf(acc1[m][f][r] + bias, 0.f);
        int off = row * 1024 + ((col * 2) ^ ((row & 7) << 4));
        *(__bf16*)((char*)h1 + off) = (__bf16)v;
      }
    }
  }
  __syncthreads();

  // ---------------- Layer 2: h2 = relu(h1 @ W2 + b2) ----------------
  f32x4 acc2[2][4];
#pragma unroll
  for (int m = 0; m < 2; ++m)
#pragma unroll
    for (int f = 0; f < 4; ++f) acc2[m][f] = FZ;

  const bf16x8* w2p = (const bf16x8*)w2s + (size_t)(w * 4) * 64 + lane;

#pragma unroll 2
  for (int t = 0; t < KT2; ++t) {
    bf16x8 afrag[2];
#pragma unroll
    for (int m = 0; m < 2; ++m) {
      int row = m * 16 + lrow;
      int off = row * 1024 + ((t * 64 + lgrp * 16) ^ ((row & 7) << 4));
      afrag[m] = *(const bf16x8*)((char*)h1 + off);
    }
    bf16x8 bfrag[4];
#pragma unroll
    for (int f = 0; f < 4; ++f)
      bfrag[f] = w2p[(size_t)(t * 16 + f) * 64];
#pragma unroll
    for (int f = 0; f < 4; ++f) {
      acc2[0][f] = __builtin_amdgcn_mfma_f32_16x16x32_bf16(afrag[0], bfrag[f], acc2[0][f], 0, 0, 0);
      acc2[1][f] = __builtin_amdgcn_mfma_f32_16x16x32_bf16(afrag[1], bfrag[f], acc2[1][f], 0, 0, 0);
    }
  }

  // epilogue 2 -> h2 (cols >= 200 get exact zeros: acc==0, bias==0)
#pragma unroll
  for (int m = 0; m < 2; ++m) {
#pragma unroll
    for (int f = 0; f < 4; ++f) {
      int col = w * 64 + f * 16 + lrow;
      float bias = sb2[col];
#pragma unroll
      for (int r = 0; r < 4; ++r) {
        int row = m * 16 + lgrp * 4 + r;
        float v = fmaxf(acc2[m][f][r] + bias, 0.f);
        int off = row * 512 + ((col * 2) ^ ((row & 7) << 4));
        *(__bf16*)((char*)h2 + off) = (__bf16)v;
      }
    }
  }
  __syncthreads();

  // ---------------- Layer 3: out = h2 @ W3 + b3 ----------------
  if (w < 2) {
    const int m = w;
    f32x4 acc3 = FZ;
#pragma unroll
    for (int t = 0; t < KT3; ++t) {
      int row = m * 16 + lrow;
      int off = row * 512 + ((t * 64 + lgrp * 16) ^ ((row & 7) << 4));
      bf16x8 a = *(const bf16x8*)((char*)h2 + off);
      bf16x8 b = ((const bf16x8*)w3s)[t * 64 + lane];
      acc3 = __builtin_amdgcn_mfma_f32_16x16x32_bf16(a, b, acc3, 0, 0, 0);
    }
    int col = lrow;
    if (col < 10) {
      float bias = b3[col];
#pragma unroll
      for (int r = 0; r < 4; ++r)
        out[(size_t)(brow + m * 16 + lgrp * 4 + r) * 10 + col] = acc3[r] + bias;
    }
  }
}

extern "C" void kernel_launch(void* const* d_in, const int* in_sizes, int n_in,
                              void* d_out, int out_size, void* d_ws, size_t ws_size,
                              hipStream_t stream) {
  const float* x  = (const float*)d_in[0];
  const float* cw = (const float*)d_in[1];
  const float* W1 = (const float*)d_in[2];
  const float* b1 = (const float*)d_in[3];
  const float* W2 = (const float*)d_in[4];
  const float* b2 = (const float*)d_in[5];
  const float* W3 = (const float*)d_in[6];
  const float* b3 = (const float*)d_in[7];
  float* out = (float*)d_out;

  __bf16* w1s = (__bf16*)d_ws;                      // 25*32*64*8 = 409600 bf16 (800 KB)
  __bf16* w2s = w1s + (size_t)KT1 * NF1 * 64 * 8;   // 16*16*64*8 = 131072 bf16 (256 KB)
  __bf16* w3s = w2s + (size_t)KT2 * NF2 * 64 * 8;   // 8*64*8     = 4096   bf16 (8 KB)

  prep_w1<<<200, 256, 0, stream>>>(W1, cw, w1s);
  prep_w2<<<64, 256, 0, stream>>>(W2, w2s);
  prep_w3<<<2, 256, 0, stream>>>(W3, w3s);

  mlp_fused<<<65536 / 32, 256, 0, stream>>>(x, w1s, w2s, w3s, b1, b2, b3, out);
}

// Round 2
// 128.872 us; speedup vs baseline: 1.3682x; 1.3682x over previous
//
#include <hip/hip_runtime.h>
#include <hip/hip_bf16.h>
#include <stdint.h>

typedef __bf16 bf16x8 __attribute__((ext_vector_type(8)));
typedef float  f32x4  __attribute__((ext_vector_type(4)));

// Geometry:
//  Layer 1: K1 = 800 (25 K-tiles of 32; k>=784 zero-padded in B), N1 = 512 (500 + pad)
//  Layer 2: K2 = 512 (500 + pad), N2 = 256 (200 + pad)
//  Layer 3: K3 = 256 (200 + pad), N3 = 16  (10 + pad)
// B operands pre-swizzled into MFMA fragment order:
//  slot = (ktile * NF + nfrag); value j of lane l = W[ktile*32 + (l>>4)*8 + j][nfrag*16 + (l&15)]
//  stored at bf16 offset (slot*64 + l)*8 -> one coalesced dwordx4 per fragment.

#define KT1 25
#define NF1 32
#define KT2 16
#define NF2 16
#define KT3 8

// ---- prep: W1eff = conv-folded W1, swizzled bf16 ----
__global__ void prep_w1(const float* __restrict__ W1, const float* __restrict__ cw,
                        __bf16* __restrict__ w1s) {
  int gid  = blockIdx.x * 256 + threadIdx.x;   // 51200 threads total
  int lane = gid & 63;
  int slot = gid >> 6;                         // 0..799
  int t = slot >> 5;                           // k-tile 0..24
  int f = slot & 31;                           // n-frag 0..31
  int kbase = t * 32 + ((lane >> 4) << 3);
  int n = f * 16 + (lane & 15);
  float c[9];
#pragma unroll
  for (int i = 0; i < 9; ++i) c[i] = cw[i];
  bf16x8 v;
#pragma unroll
  for (int e = 0; e < 8; ++e) {
    int k = kbase + e;
    float acc = 0.f;
    if (k < 784 && n < 500) {
      int pi = k / 28, pj = k % 28;
#pragma unroll
      for (int dr = 0; dr < 3; ++dr) {
        int r = pi - dr;
        if (r < 0 || r >= 26) continue;
#pragma unroll
        for (int dc = 0; dc < 3; ++dc) {
          int cc = pj - dc;
          if (cc < 0 || cc >= 26) continue;
          acc += c[dr * 3 + dc] * W1[(size_t)(r * 26 + cc) * 500 + n];
        }
      }
    }
    v[e] = (__bf16)acc;
  }
  *(bf16x8*)(w1s + (size_t)(slot * 64 + lane) * 8) = v;
}

__global__ void prep_w2(const float* __restrict__ W2, __bf16* __restrict__ w2s) {
  int gid  = blockIdx.x * 256 + threadIdx.x;   // 16384 threads
  int lane = gid & 63;
  int slot = gid >> 6;                         // 0..255
  int t = slot >> 4;
  int f = slot & 15;
  int kbase = t * 32 + ((lane >> 4) << 3);
  int n = f * 16 + (lane & 15);
  bf16x8 v;
#pragma unroll
  for (int e = 0; e < 8; ++e) {
    int k = kbase + e;
    float val = (k < 500 && n < 200) ? W2[(size_t)k * 200 + n] : 0.f;
    v[e] = (__bf16)val;
  }
  *(bf16x8*)(w2s + (size_t)(slot * 64 + lane) * 8) = v;
}

__global__ void prep_w3(const float* __restrict__ W3, __bf16* __restrict__ w3s) {
  int gid  = blockIdx.x * 256 + threadIdx.x;   // 512 threads
  int lane = gid & 63;
  int t    = gid >> 6;                         // k-tile 0..7
  int kbase = t * 32 + ((lane >> 4) << 3);
  int n = lane & 15;
  bf16x8 v;
#pragma unroll
  for (int e = 0; e < 8; ++e) {
    int k = kbase + e;
    float val = (k < 200 && n < 10) ? W3[(size_t)k * 10 + n] : 0.f;
    v[e] = (__bf16)val;
  }
  *(bf16x8*)(w3s + (size_t)(t * 64 + lane) * 8) = v;
}

// ---- fused 3-layer MLP, 64 batch rows per block, 4 waves, M=64 per wave ----
__global__ __launch_bounds__(256, 2) void mlp_fused(
    const float* __restrict__ x,
    const __bf16* __restrict__ w1s, const __bf16* __restrict__ w2s,
    const __bf16* __restrict__ w3s,
    const float* __restrict__ b1, const float* __restrict__ b2,
    const float* __restrict__ b3,
    float* __restrict__ out)
{
  // h1: 64 rows x 512 cols bf16 (row stride 1024B, XOR-swizzled). h2 reuses same space
  // (64 rows x 256 cols, row stride 512B).
  __shared__ __align__(16) char smem[64 * 1024];
  __shared__ float sb1[512];
  __shared__ float sb2[256];

  const int tid  = threadIdx.x;
  const int lane = tid & 63;
  const int w    = tid >> 6;   // wave 0..3
  const int lrow = lane & 15;
  const int lgrp = lane >> 4;  // 0..3
  const int brow = blockIdx.x * 64;

  sb1[tid]       = (tid < 500) ? b1[tid] : 0.f;
  sb1[tid + 256] = (tid + 256 < 500) ? b1[tid + 256] : 0.f;
  sb2[tid]       = (tid < 200) ? b2[tid] : 0.f;

  const f32x4 FZ = {0.f, 0.f, 0.f, 0.f};

  // ---------------- Layer 1: h1 = relu(x @ W1eff + b1) ----------------
  f32x4 acc1[4][8];
#pragma unroll
  for (int m = 0; m < 4; ++m)
#pragma unroll
    for (int f = 0; f < 8; ++f) acc1[m][f] = FZ;

  const bf16x8* w1p   = (const bf16x8*)w1s + (size_t)(w * 8) * 64 + lane;
  const float*  xbase = x + (size_t)(brow + lrow) * 784;

  bf16x8 bfr[8];     // current B tile (wave's 8 n-frags)
  f32x4  ar[4][2];   // prefetched raw x for NEXT tile
  bf16x8 afr[4];     // current A frags (bf16)

  // Branchless clamped A load: for the tail tile (t=24) lanes with k>=784 read
  // valid-but-wrong x values which multiply zero rows of w1s -> contribute 0.
  auto load_a = [&](int t) {
    int kb = t * 32 + lgrp * 8;
    if (kb > 776) kb = 776;
#pragma unroll
    for (int m = 0; m < 4; ++m) {
      const float* ap = xbase + (size_t)m * 16 * 784 + kb;
      ar[m][0] = *(const f32x4*)ap;
      ar[m][1] = *(const f32x4*)(ap + 4);
    }
  };
  auto cvt_a = [&]() {
#pragma unroll
    for (int m = 0; m < 4; ++m) {
      bf16x8 a;
#pragma unroll
      for (int e = 0; e < 4; ++e) { a[e] = (__bf16)ar[m][0][e]; a[e + 4] = (__bf16)ar[m][1][e]; }
      afr[m] = a;
    }
  };

  // prologue: tile 0 fully loaded
#pragma unroll
  for (int f = 0; f < 8; ++f) bfr[f] = w1p[(size_t)f * 64];
  load_a(0);

  for (int t = 0; t < 24; ++t) {
    cvt_a();          // consume ar(t)
    load_a(t + 1);    // refill ar for t+1 (full-iter prefetch distance)

    // first half: frags 0..3 (loaded during previous iteration's tail)
#pragma unroll
    for (int f = 0; f < 4; ++f)
#pragma unroll
      for (int m = 0; m < 4; ++m)
        acc1[m][f] = __builtin_amdgcn_mfma_f32_16x16x32_bf16(afr[m], bfr[f], acc1[m][f], 0, 0, 0);
    // refill frags 0..3 for t+1 (half-iter prefetch distance ~16 MFMA)
#pragma unroll
    for (int f = 0; f < 4; ++f)
      bfr[f] = w1p[(size_t)((t + 1) * NF1 + f) * 64];

    // second half: frags 4..7
#pragma unroll
    for (int f = 4; f < 8; ++f)
#pragma unroll
      for (int m = 0; m < 4; ++m)
        acc1[m][f] = __builtin_amdgcn_mfma_f32_16x16x32_bf16(afr[m], bfr[f], acc1[m][f], 0, 0, 0);
#pragma unroll
    for (int f = 4; f < 8; ++f)
      bfr[f] = w1p[(size_t)((t + 1) * NF1 + f) * 64];
  }
  // tail tile t=24
  cvt_a();
#pragma unroll
  for (int f = 0; f < 8; ++f)
#pragma unroll
    for (int m = 0; m < 4; ++m)
      acc1[m][f] = __builtin_amdgcn_mfma_f32_16x16x32_bf16(afr[m], bfr[f], acc1[m][f], 0, 0, 0);

  __syncthreads();   // sb1/sb2 staged; all waves ready before h1 writes

  // epilogue 1: bias + relu + bf16 -> h1 (XOR-swizzled rows)
#pragma unroll
  for (int m = 0; m < 4; ++m) {
#pragma unroll
    for (int f = 0; f < 8; ++f) {
      int col = w * 128 + f * 16 + lrow;
      float bias = sb1[col];
#pragma unroll
      for (int r = 0; r < 4; ++r) {
        int row = m * 16 + lgrp * 4 + r;
        float v = fmaxf(acc1[m][f][r] + bias, 0.f);
        int off = row * 1024 + ((col * 2) ^ ((row & 7) << 4));
        *(__bf16*)(smem + off) = (__bf16)v;
      }
    }
  }
  __syncthreads();

  // ---------------- Layer 2: h2 = relu(h1 @ W2 + b2) ----------------
  f32x4 acc2[4][4];
#pragma unroll
  for (int m = 0; m < 4; ++m)
#pragma unroll
    for (int f = 0; f < 4; ++f) acc2[m][f] = FZ;

  const bf16x8* w2p = (const bf16x8*)w2s + (size_t)(w * 4) * 64 + lane;

  bf16x8 b2a[4], b2b[4];
#pragma unroll
  for (int f = 0; f < 4; ++f) b2a[f] = w2p[(size_t)f * 64];

  for (int t = 0; t < KT2; t += 2) {
#pragma unroll
    for (int f = 0; f < 4; ++f) b2b[f] = w2p[(size_t)((t + 1) * NF2 + f) * 64];
    {
      bf16x8 a2[4];
#pragma unroll
      for (int m = 0; m < 4; ++m) {
        int row = m * 16 + lrow;
        int off = row * 1024 + ((t * 64 + lgrp * 16) ^ ((row & 7) << 4));
        a2[m] = *(const bf16x8*)(smem + off);
      }
#pragma unroll
      for (int f = 0; f < 4; ++f)
#pragma unroll
        for (int m = 0; m < 4; ++m)
          acc2[m][f] = __builtin_amdgcn_mfma_f32_16x16x32_bf16(a2[m], b2a[f], acc2[m][f], 0, 0, 0);
    }
    // prefetch t+2 (at t=14 this reads one tile past w2s -> lands in w3s region, unused)
#pragma unroll
    for (int f = 0; f < 4; ++f) b2a[f] = w2p[(size_t)((t + 2) * NF2 + f) * 64];
    {
      bf16x8 a2[4];
#pragma unroll
      for (int m = 0; m < 4; ++m) {
        int row = m * 16 + lrow;
        int off = row * 1024 + (((t + 1) * 64 + lgrp * 16) ^ ((row & 7) << 4));
        a2[m] = *(const bf16x8*)(smem + off);
      }
#pragma unroll
      for (int f = 0; f < 4; ++f)
#pragma unroll
        for (int m = 0; m < 4; ++m)
          acc2[m][f] = __builtin_amdgcn_mfma_f32_16x16x32_bf16(a2[m], b2b[f], acc2[m][f], 0, 0, 0);
    }
  }

  __syncthreads();   // all h1 reads done before overwriting with h2

  // epilogue 2 -> h2 in reused LDS (cols >= 200 exact zeros: acc==0, bias==0)
#pragma unroll
  for (int m = 0; m < 4; ++m) {
#pragma unroll
    for (int f = 0; f < 4; ++f) {
      int col = w * 64 + f * 16 + lrow;
      float bias = sb2[col];
#pragma unroll
      for (int r = 0; r < 4; ++r) {
        int row = m * 16 + lgrp * 4 + r;
        float v = fmaxf(acc2[m][f][r] + bias, 0.f);
        int off = row * 512 + ((col * 2) ^ ((row & 7) << 4));
        *(__bf16*)(smem + off) = (__bf16)v;
      }
    }
  }
  __syncthreads();

  // ---------------- Layer 3: out = h2 @ W3 + b3 (wave w owns rows w*16..w*16+15) ----------------
  {
    f32x4 acc3 = FZ;
    const bf16x8* w3p = (const bf16x8*)w3s + lane;
#pragma unroll
    for (int t = 0; t < KT3; ++t) {
      int row = w * 16 + lrow;
      int off = row * 512 + ((t * 64 + lgrp * 16) ^ ((row & 7) << 4));
      bf16x8 a = *(const bf16x8*)(smem + off);
      bf16x8 b = w3p[(size_t)t * 64];
      acc3 = __builtin_amdgcn_mfma_f32_16x16x32_bf16(a, b, acc3, 0, 0, 0);
    }
    if (lrow < 10) {
      float bias = b3[lrow];
#pragma unroll
      for (int r = 0; r < 4; ++r)
        out[(size_t)(brow + w * 16 + lgrp * 4 + r) * 10 + lrow] = acc3[r] + bias;
    }
  }
}

extern "C" void kernel_launch(void* const* d_in, const int* in_sizes, int n_in,
                              void* d_out, int out_size, void* d_ws, size_t ws_size,
                              hipStream_t stream) {
  const float* x  = (const float*)d_in[0];
  const float* cw = (const float*)d_in[1];
  const float* W1 = (const float*)d_in[2];
  const float* b1 = (const float*)d_in[3];
  const float* W2 = (const float*)d_in[4];
  const float* b2 = (const float*)d_in[5];
  const float* W3 = (const float*)d_in[6];
  const float* b3 = (const float*)d_in[7];
  float* out = (float*)d_out;

  __bf16* w1s = (__bf16*)d_ws;                      // 800 KB
  __bf16* w2s = w1s + (size_t)KT1 * NF1 * 64 * 8;   // 256 KB
  __bf16* w3s = w2s + (size_t)KT2 * NF2 * 64 * 8;   // 8 KB

  prep_w1<<<200, 256, 0, stream>>>(W1, cw, w1s);
  prep_w2<<<64, 256, 0, stream>>>(W2, w2s);
  prep_w3<<<2, 256, 0, stream>>>(W3, w3s);

  mlp_fused<<<65536 / 64, 256, 0, stream>>>(x, w1s, w2s, w3s, b1, b2, b3, out);
}